// Round 8
// baseline (300.694 us; speedup 1.0000x reference)
//
#include <hip/hip_runtime.h>
#include <hip/hip_bf16.h>

typedef __attribute__((ext_vector_type(4))) float f32x4;
typedef __attribute__((ext_vector_type(8))) short s16x8;

typedef const __attribute__((address_space(1))) void* gptr_t;
typedef __attribute__((address_space(3))) void* lptr_t;

__device__ __forceinline__ short f2b(float f){ __hip_bfloat16 h=__float2bfloat16(f); return *(short*)&h; }
__device__ __forceinline__ float b2f(short s){ __hip_bfloat16 h; *(short*)&h = s; return __bfloat162float(h); }

__device__ __forceinline__ void gl_lds16(const void* g, void* l){
  __builtin_amdgcn_global_load_lds((gptr_t)g, (lptr_t)l, 16, 0, 0);
}

// ---------------- small prep kernels ----------------

__global__ __launch_bounds__(256) void cvt_x(const float* __restrict__ X, short* __restrict__ Xb){
  int i = blockIdx.x*256 + threadIdx.x;
  const float4* p = (const float4*)(X + (size_t)i*8);
  float4 a = p[0], b = p[1];
  s16x8 o;
  o[0]=f2b(a.x); o[1]=f2b(a.y); o[2]=f2b(a.z); o[3]=f2b(a.w);
  o[4]=f2b(b.x); o[5]=f2b(b.y); o[6]=f2b(b.z); o[7]=f2b(b.w);
  *(s16x8*)(Xb + (size_t)i*8) = o;
}

__global__ __launch_bounds__(256) void cvt_wt(const float* __restrict__ W, short* __restrict__ WT){
  __shared__ short tile[64][72];
  int bl = blockIdx.x % 12, bn = blockIdx.x / 12;
  int l0 = bl*64, n0 = bn*64;
  int t = threadIdx.x;
  #pragma unroll
  for (int p=0;p<4;p++){
    int lr = p*16 + (t>>4);
    int nc = (t&15)*4;
    float4 v = *(const float4*)(W + (size_t)(l0+lr)*768 + n0 + nc);
    tile[lr][nc+0]=f2b(v.x); tile[lr][nc+1]=f2b(v.y); tile[lr][nc+2]=f2b(v.z); tile[lr][nc+3]=f2b(v.w);
  }
  __syncthreads();
  #pragma unroll
  for (int p=0;p<2;p++){
    int nr = p*32 + (t>>3);
    int lc = (t&7)*8;
    s16x8 o;
    #pragma unroll
    for(int u=0;u<8;u++) o[u] = tile[lc+u][nr];
    *(s16x8*)(WT + (size_t)(n0+nr)*768 + l0 + lc) = o;
  }
}

__global__ __launch_bounds__(256) void vtrans(const short* __restrict__ vs, short* __restrict__ vT){
  __shared__ short tile[64][72];
  int h = blockIdx.y; int i0 = blockIdx.x*64;
  int t = threadIdx.x;
  #pragma unroll
  for(int p=0;p<2;p++){
    int ir = p*32 + (t>>3); int c8=(t&7)*8;
    *(s16x8*)&tile[ir][c8] = *(const s16x8*)(vs + (size_t)(i0+ir)*768 + h*64 + c8);
  }
  __syncthreads();
  #pragma unroll
  for(int p=0;p<2;p++){
    int dr = p*32 + (t>>3); int i8=(t&7)*8;
    s16x8 o;
    #pragma unroll
    for(int u=0;u<8;u++) o[u]=tile[i8+u][dr];
    *(s16x8*)(vT + ((size_t)h*64 + dr)*1024 + i0 + i8) = o;
  }
}

// ---------------- QKV projection GEMM ----------------
__global__ __launch_bounds__(256) void qkv_gemm(const short* __restrict__ Xb, const short* __restrict__ WT,
      const float* __restrict__ bq, const float* __restrict__ bk, const float* __restrict__ bv,
      short* __restrict__ qs, short* __restrict__ ks, short* __restrict__ vs){
  __shared__ short lA[128*32], lB[128*32];
  int mat = blockIdx.y;
  const short* B = WT + (size_t)mat*768*768;
  const float* bias = mat==0?bq:(mat==1?bk:bv);
  short* outp = mat==0?qs:(mat==1?ks:vs);
  float scale = mat==0 ? 0.125f : 1.0f;
  int tm = (blockIdx.x / 6)*128, tn = (blockIdx.x % 6)*128;
  int t=threadIdx.x, wave=t>>6, lane=t&63;
  int srow=t>>2, scol=(t&3)*8;
  int wm=(wave>>1)*64, wn=(wave&1)*64;
  f32x4 acc[4][4]={};
  for (int k0=0;k0<768;k0+=32){
    #pragma unroll
    for(int r=0;r<2;++r){
      gl_lds16(Xb + (size_t)(tm+srow+r*64)*768 + k0 + scol, lA + r*2048 + wave*512);
      gl_lds16(B  + (size_t)(tn+srow+r*64)*768 + k0 + scol, lB + r*2048 + wave*512);
    }
    __syncthreads();
    int krow=(lane>>4)*8, rl=lane&15;
    s16x8 af[4], bfr[4];
    #pragma unroll
    for(int m=0;m<4;m++) af[m] = *(s16x8*)&lA[(wm+m*16+rl)*32 + krow];
    #pragma unroll
    for(int n=0;n<4;n++) bfr[n] = *(s16x8*)&lB[(wn+n*16+rl)*32 + krow];
    #pragma unroll
    for(int m=0;m<4;m++)
      #pragma unroll
      for(int n=0;n<4;n++)
        acc[m][n]=__builtin_amdgcn_mfma_f32_16x16x32_bf16(af[m],bfr[n],acc[m][n],0,0,0);
    __syncthreads();
  }
  int r0 = tm + wm + (lane>>4)*4, c0 = tn + wn + (lane&15);
  #pragma unroll
  for(int m=0;m<4;m++)
    #pragma unroll
    for(int n=0;n<4;n++){
      int col = c0 + n*16; float bb = bias[col];
      #pragma unroll
      for(int r=0;r<4;r++){
        int row = r0 + m*16 + r;
        outp[(size_t)row*768 + col] = f2b((acc[m][n][r] + bb)*scale);
      }
    }
}

// ---------------- W_G = exp(K Q^T) masked, + row sums ----------------
__global__ __launch_bounds__(256) void wg_gemm(const short* __restrict__ kb, const short* __restrict__ qb,
      const int* __restrict__ g, const float* __restrict__ am,
      short* __restrict__ WG, float* __restrict__ od){
  __shared__ short lK[128*64], lQ[128*64];
  int h=blockIdx.y;
  int tm=(blockIdx.x>>3)*128, tn=(blockIdx.x&7)*128;
  int t=threadIdx.x, wave=t>>6, lane=t&63;
  int srow=t>>3, scol=(t&7)*8;
  int wm=(wave>>1)*64, wn=(wave&1)*64;
  #pragma unroll
  for(int r=0;r<4;++r){
    gl_lds16(kb + (size_t)(tm+srow+r*32)*768 + h*64 + scol, lK + r*2048 + wave*512);
    gl_lds16(qb + (size_t)(tn+srow+r*32)*768 + h*64 + scol, lQ + r*2048 + wave*512);
  }
  __syncthreads();
  int rl=lane&15;
  f32x4 acc[4][4]={};
  #pragma unroll
  for(int ks=0;ks<2;ks++){
    int krow=ks*32+(lane>>4)*8;
    s16x8 af[4], bfr[4];
    #pragma unroll
    for(int m=0;m<4;m++) af[m]=*(s16x8*)&lK[(wm+m*16+rl)*64+krow];
    #pragma unroll
    for(int n=0;n<4;n++) bfr[n]=*(s16x8*)&lQ[(wn+n*16+rl)*64+krow];
    #pragma unroll
    for(int m=0;m<4;m++)
      #pragma unroll
      for(int n=0;n<4;n++)
        acc[m][n]=__builtin_amdgcn_mfma_f32_16x16x32_bf16(af[m],bfr[n],acc[m][n],0,0,0);
  }
  size_t hm=(size_t)h<<20;
  int r0=tm+wm+(lane>>4)*4, c0=tn+wn+rl;
  #pragma unroll
  for(int m=0;m<4;m++){
    float rs[4]={0.f,0.f,0.f,0.f};
    #pragma unroll
    for(int n=0;n<4;n++){
      int col=c0+n*16;
      bool mc = am[col] >= 0.0f;
      #pragma unroll
      for(int r=0;r<4;r++){
        int row=r0+m*16+r;
        float e = __expf(acc[m][n][r]);
        float w = (g[(size_t)row*1024+col]>0 && am[row]>=0.0f && mc) ? e : 0.f;
        WG[hm+(size_t)row*1024+col]=f2b(w);
        rs[r]+=w;
      }
    }
    #pragma unroll
    for(int r=0;r<4;r++){
      float s=rs[r];
      #pragma unroll
      for(int off=1;off<16;off<<=1) s+=__shfl_xor(s,off);
      if(rl==0) atomicAdd(&od[(h<<10)+r0+m*16+r], s);
    }
  }
}

__global__ void rhos_k(const float* __restrict__ od, float* __restrict__ rhos){
  __shared__ float red[256];
  int h = blockIdx.x, t = threadIdx.x;
  float m = -1e30f;
  for (int i=t;i<1024;i+=256) m = fmaxf(m, od[(h<<10)+i]);
  red[t]=m; __syncthreads();
  for(int s=128;s>0;s>>=1){ if(t<s) red[t]=fmaxf(red[t],red[t+s]); __syncthreads(); }
  if(t==0) rhos[h]=red[0];
}

// Am=(WG+diag(rho-od))/rho row-major; AmT row-major; plus FRAG-MAJOR copies Amf, AmTf,
// Tmf (Tm=b7*Am+b6*I, frag-only). Frag layout F[ks][rt][lane][8]:
// F[ks][rt][l][j] = M[rt*16+(l&15)][ks*32+(l>>4)*8+j]  (exact MFMA A-operand order).
__global__ __launch_bounds__(256) void amat_t(const short* __restrict__ WG, const float* __restrict__ od,
      const float* __restrict__ rhos, short* __restrict__ Am, short* __restrict__ AmT,
      short* __restrict__ Amf, short* __restrict__ AmTf, short* __restrict__ Tmf){
  __shared__ short tile[64][72];
  __shared__ short tileT[64][72];
  const float b7 = -33.f/2048.f, b6 = -21.f/1024.f;
  int h = blockIdx.y; int bx = blockIdx.x;
  int rb = bx >> 4, cb = bx & 15;
  int r0 = rb*64, c0 = cb*64;
  float rho = rhos[h]; float inv = 1.0f/fmaxf(rho,1e-30f);
  size_t hm = (size_t)h<<20;
  int t = threadIdx.x;
  #pragma unroll
  for(int p=0;p<2;p++){
    int r = p*32 + (t>>3); int c8 = (t&7)*8;
    size_t base = hm + (size_t)(r0+r)*1024 + c0 + c8;
    s16x8 w = *(const s16x8*)(WG + base);
    s16x8 oa;
    float dadd = (rho - od[(h<<10)+r0+r])*inv;
    #pragma unroll
    for(int u=0;u<8;u++){
      bool dg = (rb==cb) && ((c8+u)==r);
      float a = b2f(w[u])*inv + (dg ? dadd : 0.f);
      oa[u]=f2b(a);
      tile[r][c8+u]=oa[u];
    }
    *(s16x8*)(Am+base)=oa;
  }
  __syncthreads();
  #pragma unroll
  for(int p=0;p<2;p++){
    int c = p*32 + (t>>3); int r8 = (t&7)*8;
    s16x8 o;
    #pragma unroll
    for(int u=0;u<8;u++) o[u]=tile[r8+u][c];
    *(s16x8*)(AmT + hm + (size_t)(c0+c)*1024 + r0 + r8) = o;
    *(s16x8*)&tileT[c][r8] = o;
  }
  __syncthreads();
  int wave=t>>6, lane=t&63, rl=lane&15, krow=(lane>>4)*8;
  #pragma unroll
  for(int i=0;i<2;i++){
    int sb = wave*2 + i; int rt_l = sb>>1, ks_l = sb&1;
    s16x8 v = *(s16x8*)&tile[rt_l*16+rl][ks_l*32+krow];
    int grow = r0 + rt_l*16 + rl;
    int gcol = c0 + ks_l*32 + krow;
    s16x8 tv;
    #pragma unroll
    for(int u=0;u<8;u++){
      float a = b2f(v[u]);
      tv[u] = f2b(b7*a + ((grow == gcol+u) ? b6 : 0.f));
    }
    size_t rt = (size_t)(r0>>4) + rt_l, kss = (size_t)(c0>>5) + ks_l;
    size_t off = hm + ((kss*64 + rt)*64 + lane)*8;
    *(s16x8*)(Amf + off) = v;
    *(s16x8*)(Tmf + off) = tv;
    s16x8 wv = *(s16x8*)&tileT[rt_l*16+rl][ks_l*32+krow];
    size_t rtT = (size_t)(c0>>4) + rt_l, ksT = (size_t)(r0>>5) + ks_l;
    *(s16x8*)(AmTf + hm + ((ksT*64 + rtT)*64 + lane)*8) = wv;
  }
}

// ======== big GEMMs: 128^2 tile; A-frags coalesced from frag-major global (L2), kept ========
// ======== in-flight ACROSS the barrier via counted vmcnt(4) + raw s_barrier (T4).   ========
// ======== B LDS-dbuf (16 KiB). Issue order: B gl_lds (oldest 2) THEN 4 A-frag loads; ========
// ======== vmcnt(4) waits only the B staging; A-frag latency hides under next MFMAs. ========
#define GFSTEP(AF, AFN, CUR, KSN, DOPF) { \
  if (DOPF) { \
    _Pragma("unroll") \
    for(int r_=0;r_<2;++r_) \
      gl_lds16(Bg + (size_t)(tn+srow+r_*64)*1024 + (KSN)*32 + scol, &lB[(CUR)^1][r_*2048 + wave*512]); \
    _Pragma("unroll") \
    for(int m_=0;m_<4;m_++) AFN[m_] = *(const s16x8*)(Afw + ((size_t)((KSN)*64 + gmt + m_)<<9)); \
  } \
  s16x8 bfr_[4]; \
  _Pragma("unroll") \
  for(int n_=0;n_<4;n_++) bfr_[n_]=*(s16x8*)&lB[CUR][(wn+n_*16+rl)*32+krow]; \
  __builtin_amdgcn_s_setprio(1); \
  _Pragma("unroll") \
  for(int m_=0;m_<4;m_++) \
    _Pragma("unroll") \
    for(int n_=0;n_<4;n_++) \
      acc[m_][n_]=__builtin_amdgcn_mfma_f32_16x16x32_bf16(AF[m_],bfr_[n_],acc[m_][n_],0,0,0); \
  __builtin_amdgcn_s_setprio(0); \
  if (DOPF) { \
    asm volatile("s_waitcnt vmcnt(4)" ::: "memory"); \
    __builtin_amdgcn_s_barrier(); \
  } \
}

#define GEMMF_PROLOG \
  __shared__ short lB[2][4096]; \
  int wg = ((int)blockIdx.x & 7)*96 + ((int)blockIdx.x >> 3); \
  int h = wg >> 6; int tile = wg & 63; \
  int tm=(tile>>3)*128, tn=(tile&7)*128; \
  size_t hm=(size_t)h<<20; \
  const short* Afh = AF_ + hm; const short* Bg = B + hm; \
  int t=threadIdx.x, wave=t>>6, lane=t&63; \
  int srow=t>>2, scol=(t&3)*8; \
  int wm=(wave>>1)*64, wn=(wave&1)*64; \
  int krow=(lane>>4)*8, rl=lane&15; \
  int gmt = (tm+wm)>>4; \
  const short* Afw = Afh + (size_t)lane*8; \
  f32x4 acc[4][4]={}; \
  s16x8 afA[4], afB[4]; \
  _Pragma("unroll") \
  for(int r_=0;r_<2;++r_) \
    gl_lds16(Bg + (size_t)(tn+srow+r_*64)*1024 + scol, &lB[0][r_*2048 + wave*512]); \
  _Pragma("unroll") \
  for(int m_=0;m_<4;m_++) afA[m_] = *(const s16x8*)(Afw + ((size_t)(gmt+m_)<<9)); \
  asm volatile("s_waitcnt vmcnt(4)" ::: "memory"); \
  __builtin_amdgcn_s_barrier(); \
  _Pragma("unroll 1") \
  for(int s_=0;s_<30;s_+=2){ \
    GFSTEP(afA, afB, 0, s_+1, 1) \
    GFSTEP(afB, afA, 1, s_+2, 1) \
  } \
  GFSTEP(afA, afB, 0, 31, 1) \
  GFSTEP(afB, afA, 1, 0, 0) \
  int r0=tm+wm+(lane>>4)*4, c0=tn+wn+(lane&15);

__global__ __launch_bounds__(256) void gemma_plain(const short* __restrict__ AF_, const short* __restrict__ B,
      short* __restrict__ D){
  GEMMF_PROLOG
  short* Dg = D + hm;
  #pragma unroll
  for(int m=0;m<4;m++)
    #pragma unroll
    for(int n=0;n<4;n++){
      int col=c0+n*16;
      #pragma unroll
      for(int r=0;r<4;r++)
        Dg[(size_t)(r0+m*16+r)*1024 + col]=f2b(acc[m][n][r]);
    }
}

// G3: epilogue combine, then store FRAG-MAJOR only (V is consumed only as next A-side).
__global__ __launch_bounds__(256) void gemma_epi_fragout(const short* __restrict__ AF_, const short* __restrict__ B,
      short* __restrict__ DF, const short* __restrict__ E1, const short* __restrict__ E2,
      float c0c, float cA, float cB){
  GEMMF_PROLOG
  const short* E1g = E1 + hm; const short* E2g = E2 + hm;
  #pragma unroll
  for(int m=0;m<4;m++)
    #pragma unroll
    for(int n=0;n<4;n++){
      int col=c0+n*16;
      #pragma unroll
      for(int r=0;r<4;r++){
        int row=r0+m*16+r;
        size_t e=(size_t)row*1024+col;
        float v=acc[m][n][r]+cA*b2f(E1g[e])+cB*b2f(E2g[e]);
        if(row==col) v+=c0c;
        acc[m][n][r]=v;
      }
    }
  __shared__ short ltile[64][136];
  short* DFh = DF + hm;
  #pragma unroll
  for(int half=0; half<2; ++half){
    __syncthreads();
    if (wm == half*64){
      #pragma unroll
      for(int m=0;m<4;m++)
        #pragma unroll
        for(int n=0;n<4;n++){
          int cl = wn + n*16 + rl;
          #pragma unroll
          for(int r=0;r<4;r++)
            ltile[m*16 + (lane>>4)*4 + r][cl] = f2b(acc[m][n][r]);
        }
    }
    __syncthreads();
    #pragma unroll
    for(int i=0;i<4;i++){
      int sb = wave*4 + i; int rt_l = sb>>2, ks_l = sb&3;
      s16x8 fv = *(s16x8*)&ltile[rt_l*16+rl][ks_l*32+krow];
      size_t rt = (size_t)((tm + half*64)>>4) + rt_l;
      size_t kss = (size_t)(tn>>5) + ks_l;
      *(s16x8*)(DFh + ((kss*64 + rt)*64 + lane)*8) = fv;
    }
  }
}

__global__ __launch_bounds__(256) void gemma_epi_stat(const short* __restrict__ AF_, const short* __restrict__ B,
      short* __restrict__ D, const short* __restrict__ E1, const short* __restrict__ E2,
      float c0c, float cA, float cB, float* __restrict__ rowabs, float* __restrict__ dvp){
  GEMMF_PROLOG
  short* Dg = D + hm;
  const short* E1g = E1 + hm; const short* E2g = E2 + hm;
  #pragma unroll
  for(int m=0;m<4;m++){
    float rs[4]={0.f,0.f,0.f,0.f};
    #pragma unroll
    for(int n=0;n<4;n++){
      int col=c0+n*16;
      #pragma unroll
      for(int r=0;r<4;r++){
        int row=r0+m*16+r;
        size_t e = (size_t)row*1024 + col;
        float v = acc[m][n][r] + cA*b2f(E1g[e]) + cB*b2f(E2g[e]);
        if(row==col){ v += c0c; dvp[(h<<10)+row] = v; }
        rs[r] += fabsf(v);
        Dg[e]=f2b(v);
      }
    }
    #pragma unroll
    for(int r=0;r<4;r++){
      float s=rs[r];
      #pragma unroll
      for(int off=1;off<16;off<<=1) s+=__shfl_xor(s,off);
      if(rl==0) atomicAdd(&rowabs[(h<<10)+r0+m*16+r], s);
    }
  }
}

// ---------------- final: attn = .8*(WG/od)@v + .2*(d_i v_i - L@v)/r_i ----------------
__global__ __launch_bounds__(256) void attn_k(const short* __restrict__ WG, const short* __restrict__ L,
    const short* __restrict__ vT, const short* __restrict__ vs,
    const float* __restrict__ od, const float* __restrict__ dv, const float* __restrict__ rowabs,
    float* __restrict__ out){
  __shared__ short lW[128*32], lL[128*32], lV[64*32];
  int h=blockIdx.y, tm=blockIdx.x*128;
  size_t hm=(size_t)h<<20;
  int t=threadIdx.x, wave=t>>6, lane=t&63;
  int srow=t>>2, scol=(t&3)*8;
  f32x4 a1[2][4]={}, a2[2][4]={};
  for(int j0=0;j0<1024;j0+=32){
    #pragma unroll
    for(int r=0;r<2;++r){
      gl_lds16(WG + hm + (size_t)(tm+srow+r*64)*1024 + j0 + scol, lW + r*2048 + wave*512);
      gl_lds16(L  + hm + (size_t)(tm+srow+r*64)*1024 + j0 + scol, lL + r*2048 + wave*512);
    }
    gl_lds16(vT + ((size_t)h*64 + srow)*1024 + j0 + scol, lV + wave*512);
    __syncthreads();
    int krow=(lane>>4)*8, rl=lane&15;
    s16x8 fw[2], fl[2], fv[4];
    #pragma unroll
    for(int m=0;m<2;m++){
      fw[m]=*(s16x8*)&lW[(wave*32+m*16+rl)*32+krow];
      fl[m]=*(s16x8*)&lL[(wave*32+m*16+rl)*32+krow];
    }
    #pragma unroll
    for(int n=0;n<4;n++) fv[n]=*(s16x8*)&lV[(n*16+rl)*32+krow];
    #pragma unroll
    for(int m=0;m<2;m++)
      #pragma unroll
      for(int n=0;n<4;n++){
        a1[m][n]=__builtin_amdgcn_mfma_f32_16x16x32_bf16(fw[m],fv[n],a1[m][n],0,0,0);
        a2[m][n]=__builtin_amdgcn_mfma_f32_16x16x32_bf16(fl[m],fv[n],a2[m][n],0,0,0);
      }
    __syncthreads();
  }
  #pragma unroll
  for(int m=0;m<2;m++)
    #pragma unroll
    for(int r=0;r<4;r++){
      int row = tm + wave*32 + m*16 + (lane>>4)*4 + r;
      float invod = 1.0f/fmaxf(od[(h<<10)+row], 1e-12f);
      float dvi = dv[(h<<10)+row];
      float ivr = 1.0f/fmaxf(rowabs[(h<<10)+row] - fabsf(dvi), 1e-12f);
      #pragma unroll
      for(int n=0;n<4;n++){
        int d = n*16 + (lane&15);
        float vv = b2f(vs[(size_t)row*768 + h*64 + d]);
        out[(((size_t)h<<10)+row)*64 + d] = 0.8f*a1[m][n][r]*invod + 0.2f*(dvi*vv - a2[m][n][r])*ivr;
      }
    }
}

// ---------------- launch ----------------
extern "C" void kernel_launch(void* const* d_in, const int* in_sizes, int n_in,
                              void* d_out, int out_size, void* d_ws, size_t ws_size,
                              hipStream_t stream){
  const float* hs = (const float*)d_in[0];
  const float* Wq = (const float*)d_in[1];
  const float* bq = (const float*)d_in[2];
  const float* Wk = (const float*)d_in[3];
  const float* bk = (const float*)d_in[4];
  const float* Wv = (const float*)d_in[5];
  const float* bv = (const float*)d_in[6];
  const int*   g  = (const int*)d_in[7];
  const float* am = (const float*)d_in[8];
  float* out = (float*)d_out;

  char* w = (char*)d_ws;
  auto alloc=[&](size_t bytes)->char*{ char* p=w; w += (bytes+255)&~(size_t)255; return p; };
  short* Xb  = (short*)alloc((size_t)1024*768*2);
  short* WT  = (short*)alloc((size_t)3*768*768*2);
  short* qs  = (short*)alloc((size_t)1024*768*2);
  short* ks  = (short*)alloc((size_t)1024*768*2);
  short* vs  = (short*)alloc((size_t)1024*768*2);
  short* vT  = (short*)alloc((size_t)12*64*1024*2);
  short* WG  = (short*)alloc((size_t)12*1024*1024*2);
  short* Am  = (short*)alloc((size_t)12*1024*1024*2);
  short* AmT = (short*)alloc((size_t)12*1024*1024*2);
  short* A2  = (short*)alloc((size_t)12*1024*1024*2);
  short* A3T = (short*)alloc((size_t)12*1024*1024*2);
  short* Amf = (short*)alloc((size_t)12*1024*1024*2);  // reused as Vf after G1
  short* AmTf= (short*)alloc((size_t)12*1024*1024*2);  // reused as L after G2
  short* Tmf = (short*)alloc((size_t)12*1024*1024*2);
  float* od  = (float*)alloc((size_t)12*1024*4);
  float* rh  = (float*)alloc((size_t)64*4);
  float* dv  = (float*)alloc((size_t)12*1024*4);
  float* rab = (float*)alloc((size_t)12*1024*4);

  hipMemsetAsync(od,  0, (size_t)12*1024*4, stream);
  hipMemsetAsync(rab, 0, (size_t)12*1024*4, stream);

  cvt_x<<<384,256,0,stream>>>(hs, Xb);
  cvt_wt<<<144,256,0,stream>>>(Wq, WT);
  cvt_wt<<<144,256,0,stream>>>(Wk, WT + (size_t)768*768);
  cvt_wt<<<144,256,0,stream>>>(Wv, WT + (size_t)2*768*768);
  qkv_gemm<<<dim3(48,3),256,0,stream>>>(Xb, WT, bq,bk,bv, qs,ks,vs);
  vtrans<<<dim3(16,12),256,0,stream>>>(vs, vT);
  wg_gemm<<<dim3(64,12),256,0,stream>>>(ks, qs, g, am, WG, od);
  rhos_k<<<12,256,0,stream>>>(od, rh);
  amat_t<<<dim3(256,12),256,0,stream>>>(WG, od, rh, Am, AmT, Amf, AmTf, Tmf);

  const float b1=-0.5f, b2=-0.125f, b3=-1.f/16.f, b4=-5.f/128.f, b5=-7.f/256.f;
  short* Vf = Amf;    // Amf dead after G1
  short* L  = AmTf;   // AmTf dead after G2
  // G1: A2 = Am * Am          (A-side frag = Amf, B = AmT row-major)
  gemma_plain<<<768,256,0,stream>>>(Amf, AmT, A2);
  // G2: A3T = A^T * (A^2)^T^T = (A^3)^T   (A-side frag = AmTf, B = A2)
  gemma_plain<<<768,256,0,stream>>>(AmTf, A2, A3T);
  // G3: V = Tm * A3 + b3 I + b4 A + b5 A2   -> frag-major Vf only
  gemma_epi_fragout<<<768,256,0,stream>>>(Tmf, A3T, Vf, Am, A2, b3,b4,b5);
  // G4: L = V * A3 + I + b1 A + b2 A2   (+ fused row |L| sums and diagonal)
  gemma_epi_stat<<<768,256,0,stream>>>(Vf, A3T, L, Am, A2, 1.0f,b1,b2, rab, dv);

  attn_k<<<dim3(8,12),256,0,stream>>>(WG, L, vT, vs, od, dv, rab, out);
}

// Round 9
// 280.816 us; speedup vs baseline: 1.0708x; 1.0708x over previous
//
#include <hip/hip_runtime.h>
#include <hip/hip_bf16.h>

typedef __attribute__((ext_vector_type(4))) float f32x4;
typedef __attribute__((ext_vector_type(8))) short s16x8;

typedef const __attribute__((address_space(1))) void* gptr_t;
typedef __attribute__((address_space(3))) void* lptr_t;

__device__ __forceinline__ short f2b(float f){ __hip_bfloat16 h=__float2bfloat16(f); return *(short*)&h; }
__device__ __forceinline__ float b2f(short s){ __hip_bfloat16 h; *(short*)&h = s; return __bfloat162float(h); }

__device__ __forceinline__ void gl_lds16(const void* g, void* l){
  __builtin_amdgcn_global_load_lds((gptr_t)g, (lptr_t)l, 16, 0, 0);
}

// ---------------- small prep kernels ----------------

__global__ __launch_bounds__(256) void cvt_x(const float* __restrict__ X, short* __restrict__ Xb){
  int i = blockIdx.x*256 + threadIdx.x;
  const float4* p = (const float4*)(X + (size_t)i*8);
  float4 a = p[0], b = p[1];
  s16x8 o;
  o[0]=f2b(a.x); o[1]=f2b(a.y); o[2]=f2b(a.z); o[3]=f2b(a.w);
  o[4]=f2b(b.x); o[5]=f2b(b.y); o[6]=f2b(b.z); o[7]=f2b(b.w);
  *(s16x8*)(Xb + (size_t)i*8) = o;
}

// all three W fp32 [768][768] -> WT bf16 [3][768][768] transposed, one launch
__global__ __launch_bounds__(256) void cvt_wt3(const float* __restrict__ Wq, const float* __restrict__ Wk,
      const float* __restrict__ Wv, short* __restrict__ WT){
  __shared__ short tile[64][72];
  int mat = blockIdx.x / 144; int bx = blockIdx.x % 144;
  const float* W = mat==0?Wq:(mat==1?Wk:Wv);
  short* O = WT + (size_t)mat*768*768;
  int bl = bx % 12, bn = bx / 12;
  int l0 = bl*64, n0 = bn*64;
  int t = threadIdx.x;
  #pragma unroll
  for (int p=0;p<4;p++){
    int lr = p*16 + (t>>4);
    int nc = (t&15)*4;
    float4 v = *(const float4*)(W + (size_t)(l0+lr)*768 + n0 + nc);
    tile[lr][nc+0]=f2b(v.x); tile[lr][nc+1]=f2b(v.y); tile[lr][nc+2]=f2b(v.z); tile[lr][nc+3]=f2b(v.w);
  }
  __syncthreads();
  #pragma unroll
  for (int p=0;p<2;p++){
    int nr = p*32 + (t>>3);
    int lc = (t&7)*8;
    s16x8 o;
    #pragma unroll
    for(int u=0;u<8;u++) o[u] = tile[lc+u][nr];
    *(s16x8*)(O + (size_t)(n0+nr)*768 + l0 + lc) = o;
  }
}

// pack g>0 into bits: gb[row*32 + col/32] bit (col&31)
__global__ __launch_bounds__(256) void gpack(const int* __restrict__ g, unsigned* __restrict__ gb){
  int w = blockIdx.x*256 + threadIdx.x;   // 32768 words
  const int* p = g + (size_t)w*32;
  unsigned b=0;
  #pragma unroll
  for(int i=0;i<32;i++) b |= (p[i]>0 ? 1u:0u) << i;
  gb[w]=b;
}

__global__ __launch_bounds__(256) void vtrans(const short* __restrict__ vs, short* __restrict__ vT){
  __shared__ short tile[64][72];
  int h = blockIdx.y; int i0 = blockIdx.x*64;
  int t = threadIdx.x;
  #pragma unroll
  for(int p=0;p<2;p++){
    int ir = p*32 + (t>>3); int c8=(t&7)*8;
    *(s16x8*)&tile[ir][c8] = *(const s16x8*)(vs + (size_t)(i0+ir)*768 + h*64 + c8);
  }
  __syncthreads();
  #pragma unroll
  for(int p=0;p<2;p++){
    int dr = p*32 + (t>>3); int i8=(t&7)*8;
    s16x8 o;
    #pragma unroll
    for(int u=0;u<8;u++) o[u]=tile[i8+u][dr];
    *(s16x8*)(vT + ((size_t)h*64 + dr)*1024 + i0 + i8) = o;
  }
}

// ---------------- QKV projection GEMM ----------------
__global__ __launch_bounds__(256) void qkv_gemm(const short* __restrict__ Xb, const short* __restrict__ WT,
      const float* __restrict__ bq, const float* __restrict__ bk, const float* __restrict__ bv,
      short* __restrict__ qs, short* __restrict__ ks, short* __restrict__ vs){
  __shared__ short lA[128*32], lB[128*32];
  int mat = blockIdx.y;
  const short* B = WT + (size_t)mat*768*768;
  const float* bias = mat==0?bq:(mat==1?bk:bv);
  short* outp = mat==0?qs:(mat==1?ks:vs);
  float scale = mat==0 ? 0.125f : 1.0f;
  int tm = (blockIdx.x / 6)*128, tn = (blockIdx.x % 6)*128;
  int t=threadIdx.x, wave=t>>6, lane=t&63;
  int srow=t>>2, scol=(t&3)*8;
  int wm=(wave>>1)*64, wn=(wave&1)*64;
  f32x4 acc[4][4]={};
  for (int k0=0;k0<768;k0+=32){
    #pragma unroll
    for(int r=0;r<2;++r){
      gl_lds16(Xb + (size_t)(tm+srow+r*64)*768 + k0 + scol, lA + r*2048 + wave*512);
      gl_lds16(B  + (size_t)(tn+srow+r*64)*768 + k0 + scol, lB + r*2048 + wave*512);
    }
    __syncthreads();
    int krow=(lane>>4)*8, rl=lane&15;
    s16x8 af[4], bfr[4];
    #pragma unroll
    for(int m=0;m<4;m++) af[m] = *(s16x8*)&lA[(wm+m*16+rl)*32 + krow];
    #pragma unroll
    for(int n=0;n<4;n++) bfr[n] = *(s16x8*)&lB[(wn+n*16+rl)*32 + krow];
    #pragma unroll
    for(int m=0;m<4;m++)
      #pragma unroll
      for(int n=0;n<4;n++)
        acc[m][n]=__builtin_amdgcn_mfma_f32_16x16x32_bf16(af[m],bfr[n],acc[m][n],0,0,0);
    __syncthreads();
  }
  int r0 = tm + wm + (lane>>4)*4, c0 = tn + wn + (lane&15);
  #pragma unroll
  for(int m=0;m<4;m++)
    #pragma unroll
    for(int n=0;n<4;n++){
      int col = c0 + n*16; float bb = bias[col];
      #pragma unroll
      for(int r=0;r<4;r++){
        int row = r0 + m*16 + r;
        outp[(size_t)row*768 + col] = f2b((acc[m][n][r] + bb)*scale);
      }
    }
}

// ---------------- W_G = exp(K Q^T) masked (bitmask), + row sums ----------------
__global__ __launch_bounds__(256) void wg_gemm(const short* __restrict__ kb, const short* __restrict__ qb,
      const unsigned* __restrict__ gb, const float* __restrict__ am,
      short* __restrict__ WG, float* __restrict__ od){
  __shared__ short lK[128*64], lQ[128*64];
  int h=blockIdx.y;
  int tm=(blockIdx.x>>3)*128, tn=(blockIdx.x&7)*128;
  int t=threadIdx.x, wave=t>>6, lane=t&63;
  int srow=t>>3, scol=(t&7)*8;
  int wm=(wave>>1)*64, wn=(wave&1)*64;
  #pragma unroll
  for(int r=0;r<4;++r){
    gl_lds16(kb + (size_t)(tm+srow+r*32)*768 + h*64 + scol, lK + r*2048 + wave*512);
    gl_lds16(qb + (size_t)(tn+srow+r*32)*768 + h*64 + scol, lQ + r*2048 + wave*512);
  }
  __syncthreads();
  int rl=lane&15;
  f32x4 acc[4][4]={};
  #pragma unroll
  for(int ks=0;ks<2;ks++){
    int krow=ks*32+(lane>>4)*8;
    s16x8 af[4], bfr[4];
    #pragma unroll
    for(int m=0;m<4;m++) af[m]=*(s16x8*)&lK[(wm+m*16+rl)*64+krow];
    #pragma unroll
    for(int n=0;n<4;n++) bfr[n]=*(s16x8*)&lQ[(wn+n*16+rl)*64+krow];
    #pragma unroll
    for(int m=0;m<4;m++)
      #pragma unroll
      for(int n=0;n<4;n++)
        acc[m][n]=__builtin_amdgcn_mfma_f32_16x16x32_bf16(af[m],bfr[n],acc[m][n],0,0,0);
  }
  size_t hm=(size_t)h<<20;
  int r0=tm+wm+(lane>>4)*4, c0=tn+wn+rl;
  #pragma unroll
  for(int m=0;m<4;m++){
    float rs[4]={0.f,0.f,0.f,0.f};
    #pragma unroll
    for(int n=0;n<4;n++){
      int col=c0+n*16;
      bool mc = am[col] >= 0.0f;
      unsigned sh = col & 31; int wofs = col >> 5;
      #pragma unroll
      for(int r=0;r<4;r++){
        int row=r0+m*16+r;
        float e = __expf(acc[m][n][r]);
        bool gbit = (gb[(row<<5) + wofs] >> sh) & 1u;
        float w = (gbit && am[row]>=0.0f && mc) ? e : 0.f;
        WG[hm+(size_t)row*1024+col]=f2b(w);
        rs[r]+=w;
      }
    }
    #pragma unroll
    for(int r=0;r<4;r++){
      float s=rs[r];
      #pragma unroll
      for(int off=1;off<16;off<<=1) s+=__shfl_xor(s,off);
      if(rl==0) atomicAdd(&od[(h<<10)+r0+m*16+r], s);
    }
  }
}

__global__ void rhos_k(const float* __restrict__ od, float* __restrict__ rhos){
  __shared__ float red[256];
  int h = blockIdx.x, t = threadIdx.x;
  float m = -1e30f;
  for (int i=t;i<1024;i+=256) m = fmaxf(m, od[(h<<10)+i]);
  red[t]=m; __syncthreads();
  for(int s=128;s>0;s>>=1){ if(t<s) red[t]=fmaxf(red[t],red[t+s]); __syncthreads(); }
  if(t==0) rhos[h]=red[0];
}

// Am = (WG + diag(rho-od))/rho ; AmT = Am^T ; T = b7*Am + b6*I
__global__ __launch_bounds__(256) void amat_t(const short* __restrict__ WG, const float* __restrict__ od,
      const float* __restrict__ rhos, short* __restrict__ Am, short* __restrict__ AmT,
      short* __restrict__ T){
  __shared__ short tile[64][72];
  const float b7 = -33.f/2048.f, b6 = -21.f/1024.f;
  int h = blockIdx.y; int bx = blockIdx.x;
  int rb = bx >> 4, cb = bx & 15;
  int r0 = rb*64, c0 = cb*64;
  float rho = rhos[h]; float inv = 1.0f/fmaxf(rho,1e-30f);
  size_t hm = (size_t)h<<20;
  int t = threadIdx.x;
  #pragma unroll
  for(int p=0;p<2;p++){
    int r = p*32 + (t>>3); int c8 = (t&7)*8;
    size_t base = hm + (size_t)(r0+r)*1024 + c0 + c8;
    s16x8 w = *(const s16x8*)(WG + base);
    s16x8 oa, ot;
    float dadd = (rho - od[(h<<10)+r0+r])*inv;
    #pragma unroll
    for(int u=0;u<8;u++){
      bool dg = (rb==cb) && ((c8+u)==r);
      float a = b2f(w[u])*inv + (dg ? dadd : 0.f);
      oa[u]=f2b(a);
      ot[u]=f2b(b7*a + (dg ? b6 : 0.f));
      tile[r][c8+u]=oa[u];
    }
    *(s16x8*)(Am+base)=oa; *(s16x8*)(T+base)=ot;
  }
  __syncthreads();
  #pragma unroll
  for(int p=0;p<2;p++){
    int c = p*32 + (t>>3); int r8 = (t&7)*8;
    s16x8 o;
    #pragma unroll
    for(int u=0;u<8;u++) o[u]=tile[r8+u][c];
    *(s16x8*)(AmT + hm + (size_t)(c0+c)*1024 + r0 + r8) = o;
  }
}

// ======== big GEMMs: 128^2 tile, double-buffered BK=32 (round-5 proven structure), ========
// ======== T1 XCD swizzle, bump-pointer staging addresses (cut per-step VALU).       ========
#define GEMM2P_PROLOG \
  __shared__ short lA[2][4096], lB[2][4096]; \
  int wg = ((int)blockIdx.x & 7)*96 + ((int)blockIdx.x >> 3); \
  int h = wg >> 6; int tile = wg & 63; \
  int tm=(tile>>3)*128, tn=(tile&7)*128; \
  size_t hm=(size_t)h<<20; \
  const short* Ag = A + hm; const short* Bg = B + hm; \
  int t=threadIdx.x, wave=t>>6, lane=t&63; \
  int srow=t>>2, scol=(t&3)*8; \
  int wm=(wave>>1)*64, wn=(wave&1)*64; \
  int krow=(lane>>4)*8, rl=lane&15; \
  const short* pA0 = Ag + (size_t)(tm+srow)*1024 + scol; \
  const short* pA1 = pA0 + (size_t)64*1024; \
  const short* pB0 = Bg + (size_t)(tn+srow)*1024 + scol; \
  const short* pB1 = pB0 + (size_t)64*1024; \
  f32x4 acc[4][4]={}; \
  gl_lds16(pA0, &lA[0][wave*512]); \
  gl_lds16(pA1, &lA[0][2048 + wave*512]); \
  gl_lds16(pB0, &lB[0][wave*512]); \
  gl_lds16(pB1, &lB[0][2048 + wave*512]); \
  pA0+=32; pA1+=32; pB0+=32; pB1+=32; \
  __syncthreads(); \
  int cur=0; \
  _Pragma("unroll 1") \
  for(int k0=32;k0<1024;k0+=32){ \
    gl_lds16(pA0, &lA[cur^1][wave*512]); \
    gl_lds16(pA1, &lA[cur^1][2048 + wave*512]); \
    gl_lds16(pB0, &lB[cur^1][wave*512]); \
    gl_lds16(pB1, &lB[cur^1][2048 + wave*512]); \
    pA0+=32; pA1+=32; pB0+=32; pB1+=32; \
    s16x8 af[4], bfr[4]; \
    _Pragma("unroll") \
    for(int m=0;m<4;m++) af[m]=*(s16x8*)&lA[cur][(wm+m*16+rl)*32+krow]; \
    _Pragma("unroll") \
    for(int n=0;n<4;n++) bfr[n]=*(s16x8*)&lB[cur][(wn+n*16+rl)*32+krow]; \
    __builtin_amdgcn_s_setprio(1); \
    _Pragma("unroll") \
    for(int m=0;m<4;m++) \
      _Pragma("unroll") \
      for(int n=0;n<4;n++) \
        acc[m][n]=__builtin_amdgcn_mfma_f32_16x16x32_bf16(af[m],bfr[n],acc[m][n],0,0,0); \
    __builtin_amdgcn_s_setprio(0); \
    __syncthreads(); \
    cur^=1; \
  } \
  { s16x8 af[4], bfr[4]; \
    _Pragma("unroll") \
    for(int m=0;m<4;m++) af[m]=*(s16x8*)&lA[cur][(wm+m*16+rl)*32+krow]; \
    _Pragma("unroll") \
    for(int n=0;n<4;n++) bfr[n]=*(s16x8*)&lB[cur][(wn+n*16+rl)*32+krow]; \
    __builtin_amdgcn_s_setprio(1); \
    _Pragma("unroll") \
    for(int m=0;m<4;m++) \
      _Pragma("unroll") \
      for(int n=0;n<4;n++) \
        acc[m][n]=__builtin_amdgcn_mfma_f32_16x16x32_bf16(af[m],bfr[n],acc[m][n],0,0,0); \
    __builtin_amdgcn_s_setprio(0); \
  } \
  int r0=tm+wm+(lane>>4)*4, c0=tn+wn+(lane&15);

__global__ __launch_bounds__(256) void gemm2p_plain(const short* __restrict__ A, const short* __restrict__ B,
      short* __restrict__ D){
  GEMM2P_PROLOG
  short* Dg = D + hm;
  #pragma unroll
  for(int m=0;m<4;m++)
    #pragma unroll
    for(int n=0;n<4;n++){
      int col=c0+n*16;
      #pragma unroll
      for(int r=0;r<4;r++)
        Dg[(size_t)(r0+m*16+r)*1024 + col]=f2b(acc[m][n][r]);
    }
}

__global__ __launch_bounds__(256) void gemm2p_epi(const short* __restrict__ A, const short* __restrict__ B,
      short* __restrict__ D, const short* __restrict__ E1, const short* __restrict__ E2,
      float c0c, float cA, float cB){
  GEMM2P_PROLOG
  short* Dg = D + hm;
  const short* E1g = E1 + hm; const short* E2g = E2 + hm;
  #pragma unroll
  for(int m=0;m<4;m++)
    #pragma unroll
    for(int n=0;n<4;n++){
      int col=c0+n*16;
      #pragma unroll
      for(int r=0;r<4;r++){
        int row=r0+m*16+r;
        size_t e = (size_t)row*1024 + col;
        float v = acc[m][n][r] + cA*b2f(E1g[e]) + cB*b2f(E2g[e]);
        if(row==col) v += c0c;
        Dg[e]=f2b(v);
      }
    }
}

__global__ __launch_bounds__(256) void gemm2p_epi_stat(const short* __restrict__ A, const short* __restrict__ B,
      short* __restrict__ D, const short* __restrict__ E1, const short* __restrict__ E2,
      float c0c, float cA, float cB, float* __restrict__ rowabs, float* __restrict__ dvp){
  GEMM2P_PROLOG
  short* Dg = D + hm;
  const short* E1g = E1 + hm; const short* E2g = E2 + hm;
  #pragma unroll
  for(int m=0;m<4;m++){
    float rs[4]={0.f,0.f,0.f,0.f};
    #pragma unroll
    for(int n=0;n<4;n++){
      int col=c0+n*16;
      #pragma unroll
      for(int r=0;r<4;r++){
        int row=r0+m*16+r;
        size_t e = (size_t)row*1024 + col;
        float v = acc[m][n][r] + cA*b2f(E1g[e]) + cB*b2f(E2g[e]);
        if(row==col){ v += c0c; dvp[(h<<10)+row] = v; }
        rs[r] += fabsf(v);
        Dg[e]=f2b(v);
      }
    }
    #pragma unroll
    for(int r=0;r<4;r++){
      float s=rs[r];
      #pragma unroll
      for(int off=1;off<16;off<<=1) s+=__shfl_xor(s,off);
      if(rl==0) atomicAdd(&rowabs[(h<<10)+r0+m*16+r], s);
    }
  }
}

// ---------------- final: attn = .8*(WG/od)@v + .2*(d_i v_i - L@v)/r_i ----------------
// 64-row tiles (192 blocks) for 2x parallelism of this latency-bound kernel.
__global__ __launch_bounds__(256) void attn_k(const short* __restrict__ WG, const short* __restrict__ L,
    const short* __restrict__ vT, const short* __restrict__ vs,
    const float* __restrict__ od, const float* __restrict__ dv, const float* __restrict__ rowabs,
    float* __restrict__ out){
  __shared__ short lW[64*32], lL[64*32], lV[64*32];
  int h=blockIdx.y, tm=blockIdx.x*64;
  size_t hm=(size_t)h<<20;
  int t=threadIdx.x, wave=t>>6, lane=t&63;
  int srow=t>>2, scol=(t&3)*8;
  f32x4 a1[4]={}, a2[4]={};
  for(int j0=0;j0<1024;j0+=32){
    gl_lds16(WG + hm + (size_t)(tm+srow)*1024 + j0 + scol, lW + wave*512);
    gl_lds16(L  + hm + (size_t)(tm+srow)*1024 + j0 + scol, lL + wave*512);
    gl_lds16(vT + ((size_t)h*64 + srow)*1024 + j0 + scol, lV + wave*512);
    __syncthreads();
    int krow=(lane>>4)*8, rl=lane&15;
    s16x8 fw, fl, fv[4];
    fw=*(s16x8*)&lW[(wave*16+rl)*32+krow];
    fl=*(s16x8*)&lL[(wave*16+rl)*32+krow];
    #pragma unroll
    for(int n=0;n<4;n++) fv[n]=*(s16x8*)&lV[(n*16+rl)*32+krow];
    #pragma unroll
    for(int n=0;n<4;n++){
      a1[n]=__builtin_amdgcn_mfma_f32_16x16x32_bf16(fw,fv[n],a1[n],0,0,0);
      a2[n]=__builtin_amdgcn_mfma_f32_16x16x32_bf16(fl,fv[n],a2[n],0,0,0);
    }
    __syncthreads();
  }
  #pragma unroll
  for(int r=0;r<4;r++){
    int row = tm + wave*16 + (lane>>4)*4 + r;
    float invod = 1.0f/fmaxf(od[(h<<10)+row], 1e-12f);
    float dvi = dv[(h<<10)+row];
    float ivr = 1.0f/fmaxf(rowabs[(h<<10)+row] - fabsf(dvi), 1e-12f);
    #pragma unroll
    for(int n=0;n<4;n++){
      int d = n*16 + (lane&15);
      float vv = b2f(vs[(size_t)row*768 + h*64 + d]);
      out[(((size_t)h<<10)+row)*64 + d] = 0.8f*a1[n][r]*invod + 0.2f*(dvi*vv - a2[n][r])*ivr;
    }
  }
}

// ---------------- launch ----------------
extern "C" void kernel_launch(void* const* d_in, const int* in_sizes, int n_in,
                              void* d_out, int out_size, void* d_ws, size_t ws_size,
                              hipStream_t stream){
  const float* hs = (const float*)d_in[0];
  const float* Wq = (const float*)d_in[1];
  const float* bq = (const float*)d_in[2];
  const float* Wk = (const float*)d_in[3];
  const float* bk = (const float*)d_in[4];
  const float* Wv = (const float*)d_in[5];
  const float* bv = (const float*)d_in[6];
  const int*   g  = (const int*)d_in[7];
  const float* am = (const float*)d_in[8];
  float* out = (float*)d_out;

  char* w = (char*)d_ws;
  auto alloc=[&](size_t bytes)->char*{ char* p=w; w += (bytes+255)&~(size_t)255; return p; };
  short* Xb  = (short*)alloc((size_t)1024*768*2);
  short* WT  = (short*)alloc((size_t)3*768*768*2);
  short* qs  = (short*)alloc((size_t)1024*768*2);
  short* ks  = (short*)alloc((size_t)1024*768*2);
  short* vs  = (short*)alloc((size_t)1024*768*2);
  short* vT  = (short*)alloc((size_t)12*64*1024*2);
  unsigned* gb = (unsigned*)alloc((size_t)1024*32*4);
  short* WG  = (short*)alloc((size_t)12*1024*1024*2);
  short* Am  = (short*)alloc((size_t)12*1024*1024*2);
  short* AmT = (short*)alloc((size_t)12*1024*1024*2);  // later reused as V
  short* Tm  = (short*)alloc((size_t)12*1024*1024*2);  // later reused as L
  short* A2  = (short*)alloc((size_t)12*1024*1024*2);
  short* A3T = (short*)alloc((size_t)12*1024*1024*2);
  float* od  = (float*)alloc((size_t)2*12*1024*4);     // od + rab contiguous, one memset
  float* rab = od + 12*1024;
  float* rh  = (float*)alloc((size_t)64*4);
  float* dv  = (float*)alloc((size_t)12*1024*4);

  hipMemsetAsync(od, 0, (size_t)2*12*1024*4, stream);

  cvt_x<<<384,256,0,stream>>>(hs, Xb);
  cvt_wt3<<<432,256,0,stream>>>(Wq, Wk, Wv, WT);
  gpack<<<128,256,0,stream>>>(g, gb);
  qkv_gemm<<<dim3(48,3),256,0,stream>>>(Xb, WT, bq,bk,bv, qs,ks,vs);
  vtrans<<<dim3(16,12),256,0,stream>>>(vs, vT);
  wg_gemm<<<dim3(64,12),256,0,stream>>>(ks, qs, gb, am, WG, od);
  rhos_k<<<12,256,0,stream>>>(od, rh);
  amat_t<<<dim3(256,12),256,0,stream>>>(WG, od, rh, Am, AmT, Tm);

  const float b1=-0.5f, b2=-0.125f, b3=-1.f/16.f, b4=-5.f/128.f, b5=-7.f/256.f;
  short* V = AmT;   // AmT dead after G2
  short* L = Tm;    // Tm dead after G3
  // G1: A2 = Am * AmT^T (= A^2)
  gemm2p_plain<<<768,256,0,stream>>>(Am, AmT, A2);
  // G2: A3T = AmT * A2^T (= (A^3)^T)
  gemm2p_plain<<<768,256,0,stream>>>(AmT, A2, A3T);
  // G3: V = T * A3 + b3 I + b4 A + b5 A2
  gemm2p_epi<<<768,256,0,stream>>>(Tm, A3T, V, Am, A2, b3,b4,b5);
  // G4: L = V * A3 + I + b1 A + b2 A2   (+ fused row |L| sums and diagonal)
  gemm2p_epi_stat<<<768,256,0,stream>>>(V, A3T, L, Am, A2, 1.0f,b1,b2, rab, dv);

  attn_k<<<dim3(16,12),256,0,stream>>>(WG, L, vT, vs, od, dv, rab, out);
}